// Round 6
// baseline (1729.696 us; speedup 1.0000x reference)
//
#include <hip/hip_runtime.h>

#define DEV __device__ __forceinline__

typedef short s16x8 __attribute__((ext_vector_type(8)));
typedef float f32x4 __attribute__((ext_vector_type(4)));
typedef _Float16 h16x2 __attribute__((ext_vector_type(2)));
typedef unsigned short u16;
typedef unsigned long long u64;

constexpr int Wn = 128;    // words
constexpr int Pn = 4096;   // phrases
constexpr int Rn = 8192;   // relations
constexpr int Hn = 1024;   // hidden

DEV float b2f(u16 u) { union { unsigned i; float f; } x; x.i = (unsigned)u << 16; return x.f; }
DEV u16 f2b(float f) {
  union { float f; unsigned i; } x; x.f = f;
  unsigned r = x.i + 0x7FFF + ((x.i >> 16) & 1);   // RNE
  return (u16)(r >> 16);
}
DEV float leaky(float x) { return x >= 0.f ? x : 0.01f * x; }

DEV void load_lds16(const void* g, void* l) {
  __builtin_amdgcn_global_load_lds(
      (const __attribute__((address_space(1))) void*)g,
      (__attribute__((address_space(3))) void*)l, 16, 0, 0);
}

DEV float wred_sum(float v) {
  #pragma unroll
  for (int m = 1; m < 64; m <<= 1) v += __shfl_xor(v, m, 64);
  return v;
}
DEV float wred_max(float v) {
  #pragma unroll
  for (int m = 1; m < 64; m <<= 1) v = fmaxf(v, __shfl_xor(v, m, 64));
  return v;
}

// f32 -> bf16 row-block convert. Row length is always 1024 elements;
// unit u: row = u>>7, col = (u&127)*8.
__global__ __launch_bounds__(256) void k_cvt(
    const float* __restrict__ src, int sld, u16* __restrict__ dst)
{
  int g = blockIdx.x * 256 + threadIdx.x;
  int row = g >> 7, c = (g & 127) * 8;
  const float* s = src + (size_t)row * sld + c;
  float4 a = *(const float4*)s;
  float4 b = *(const float4*)(s + 4);
  ushort4 lo = {f2b(a.x), f2b(a.y), f2b(a.z), f2b(a.w)};
  ushort4 hi = {f2b(b.x), f2b(b.y), f2b(b.z), f2b(b.w)};
  *(ushort4*)(dst + (size_t)row * 1024 + c) = lo;
  *(ushort4*)(dst + (size_t)row * 1024 + c + 4) = hi;
}

// ---------------------------------------------------------------------------
// GEMM (B^T form): C[M,N] = epilogue( A[M,K] @ B[N,K]^T ).  A,B bf16 row-major.
// 128x128 tile, BK=64, 256 threads (4 waves, each 64x64 via 4x4 16x16x32 MFMA).
// ---------------------------------------------------------------------------
template<bool OUTF32, bool ACT, bool BIAS, bool RES, bool DUAL>
__global__ __launch_bounds__(256) void k_gemm_bt(
    const u16* __restrict__ A, int lda,
    const u16* __restrict__ B, int ldb,
    void* Cp, int ldc,
    const float* __restrict__ bias,
    const float* res, int ldr,
    u16* C16,
    float alpha, int K)
{
  __shared__ __align__(16) char sm[32768];
  char* As = sm;
  char* Bs = sm + 16384;
  const int tid = threadIdx.x;
  const int lane = tid & 63, w = tid >> 6;
  const int m0 = blockIdx.y * 128, n0 = blockIdx.x * 128;
  const int wr = (w >> 1) * 64, wc = (w & 1) * 64;
  const int r_lo = lane & 15, kq = lane >> 4;

  f32x4 acc[4][4];
  #pragma unroll
  for (int i = 0; i < 4; ++i)
    #pragma unroll
    for (int j = 0; j < 4; ++j) acc[i][j] = (f32x4){0.f, 0.f, 0.f, 0.f};

  for (int kt = 0; kt < K; kt += 64) {
    if (kt) __syncthreads();
    #pragma unroll
    for (int i = 0; i < 4; ++i) {        // stage A (4 x 4KB)
      int f = i * 4096 + tid * 16;
      int row = f >> 7, colb = f & 127;
      int scol = colb ^ ((row & 7) << 4);
      const char* src = (const char*)(A + (size_t)(m0 + row) * lda + kt) + scol;
      load_lds16(src, As + i * 4096 + w * 1024);
    }
    #pragma unroll
    for (int i = 0; i < 4; ++i) {        // stage B
      int f = i * 4096 + tid * 16;
      int row = f >> 7, colb = f & 127;
      int scol = colb ^ ((row & 7) << 4);
      const char* src = (const char*)(B + (size_t)(n0 + row) * ldb + kt) + scol;
      load_lds16(src, Bs + i * 4096 + w * 1024);
    }
    __syncthreads();
    #pragma unroll
    for (int ks = 0; ks < 2; ++ks) {
      s16x8 af[4], bfr[4];
      const int kb = ks * 64 + kq * 16;
      #pragma unroll
      for (int mi = 0; mi < 4; ++mi) {
        int row = wr + mi * 16 + r_lo;
        af[mi] = *(const s16x8*)(As + row * 128 + (kb ^ ((row & 7) << 4)));
      }
      #pragma unroll
      for (int ni = 0; ni < 4; ++ni) {
        int row = wc + ni * 16 + r_lo;
        bfr[ni] = *(const s16x8*)(Bs + row * 128 + (kb ^ ((row & 7) << 4)));
      }
      #pragma unroll
      for (int mi = 0; mi < 4; ++mi)
        #pragma unroll
        for (int ni = 0; ni < 4; ++ni)
          acc[mi][ni] = __builtin_amdgcn_mfma_f32_16x16x32_bf16(af[mi], bfr[ni], acc[mi][ni], 0, 0, 0);
    }
  }

  #pragma unroll
  for (int mi = 0; mi < 4; ++mi) {
    #pragma unroll
    for (int ni = 0; ni < 4; ++ni) {
      #pragma unroll
      for (int j = 0; j < 4; ++j) {
        int r = m0 + wr + mi * 16 + kq * 4 + j;
        int c = n0 + wc + ni * 16 + r_lo;
        float v = acc[mi][ni][j] * alpha;
        if (BIAS) v += bias[c];
        if (RES)  v += res[(size_t)r * ldr + c];
        if (ACT)  v = leaky(v);
        if (OUTF32) ((float*)Cp)[(size_t)r * ldc + c] = v;
        else        ((u16*)Cp)[(size_t)r * ldc + c] = f2b(v);
        if (DUAL)   C16[(size_t)r * ldc + c] = f2b(v);
      }
    }
  }
}

// ---------------------------------------------------------------------------
// Fused GRU + conversions. Blocks 0..31: bidirectional GRU scan (16 blocks
// per direction, 96 gates x 512 f16 weights in LDS). Cross-block exchange via
// tagged u64 relaxed agent atomics; ONE dedicated poll wave per block (wave 0,
// 8 elems/lane, parallel reloads + s_sleep backoff) while waves 1-3 wait at
// the barrier. Blocks 32+: grid-stride f32->bf16 conversion task list,
// running concurrently on the otherwise-idle CUs.
// ---------------------------------------------------------------------------
struct CvtTask { const float* src; u16* dst; int sld; int units; };
struct CvtTasks { CvtTask t[10]; int n; };

__global__ __launch_bounds__(256) void k_gru_fused(
    const float* __restrict__ w_hh_f, const float* __restrict__ w_hh_b,
    const float* __restrict__ b_hh_f, const float* __restrict__ b_hh_b,
    const float* __restrict__ gi_f, const float* __restrict__ gi_b,
    u64* __restrict__ X, float* __restrict__ ctx, CvtTasks T)
{
  __shared__ __align__(16) u16 wlds[96 * 512];   // f16 bits (96KB)
  __shared__ float bh[96];
  __shared__ float hfull[512];
  __shared__ float ghl[96];

  const int bid = blockIdx.x;
  const int tid = threadIdx.x;

  if (bid >= 32) {                       // ---- conversion tasks ----
    int bc = bid - 32;
    int nb = (int)gridDim.x - 32;
    for (int k = 0; k < T.n; ++k) {
      const float* src = T.t[k].src;
      u16* dst = T.t[k].dst;
      int sld = T.t[k].sld;
      int units = T.t[k].units;
      for (int u = bc * 256 + tid; u < units; u += nb * 256) {
        int row = u >> 7, c = (u & 127) * 8;
        const float* s = src + (size_t)row * sld + c;
        float4 a = *(const float4*)s;
        float4 b = *(const float4*)(s + 4);
        ushort4 lo = {f2b(a.x), f2b(a.y), f2b(a.z), f2b(a.w)};
        ushort4 hi = {f2b(b.x), f2b(b.y), f2b(b.z), f2b(b.w)};
        *(ushort4*)(dst + (size_t)row * 1024 + c) = lo;
        *(ushort4*)(dst + (size_t)row * 1024 + c + 4) = hi;
      }
    }
    return;
  }

  // ---- GRU ----
  const int dir = bid >> 4;
  const int b   = bid & 15;
  const int lane = tid & 63, wv = tid >> 6;

  const float* w_hh = dir ? w_hh_b : w_hh_f;
  const float* b_hh = dir ? b_hh_b : b_hh_f;
  const float* gi = dir ? gi_b : gi_f;
  u64* myX = X + (size_t)dir * 128 * 512;

  for (int idx = tid; idx < 96 * 128; idx += 256) {   // weights f32 -> f16 LDS
    int gl = idx >> 7;
    int kc = (idx & 127) << 2;
    int g = 32 * b + (gl & 31) + ((gl >> 5) << 9);
    float4 wv4 = *(const float4*)(w_hh + (size_t)g * 512 + kc);
    u16 dst[4];
    _Float16 h0 = (_Float16)wv4.x; __builtin_memcpy(&dst[0], &h0, 2);
    _Float16 h1 = (_Float16)wv4.y; __builtin_memcpy(&dst[1], &h1, 2);
    _Float16 h2 = (_Float16)wv4.z; __builtin_memcpy(&dst[2], &h2, 2);
    _Float16 h3 = (_Float16)wv4.w; __builtin_memcpy(&dst[3], &h3, 2);
    *(uint2*)(wlds + gl * 512 + kc) = *(uint2*)dst;
  }
  if (tid < 96) {
    int g = 32 * b + (tid & 31) + ((tid >> 5) << 9);
    bh[tid] = b_hh[g];
  }
  __syncthreads();

  h16x2 hh[4];
  #pragma unroll
  for (int i = 0; i < 4; ++i) { hh[i][0] = (_Float16)0.f; hh[i][1] = (_Float16)0.f; }
  float hprev = 0.f;                    // tid<32: own h element
  const int jg = 32 * b + tid;          // valid for tid<32

  for (int sidx = 0; sidx < 128; ++sidx) {
    const int t = dir ? (127 - sidx) : sidx;

    float gir = 0.f, giz = 0.f, gin = 0.f;
    if (tid < 32) {                     // prefetch (hides under dot phase)
      gir = gi[t * 1536 + jg];
      giz = gi[t * 1536 + 512 + jg];
      gin = gi[t * 1536 + 1024 + jg];
    }

    for (int gg = 0; gg < 24; ++gg) {   // wave wv handles gates wv*24..+24
      int gl = wv * 24 + gg;
      const h16x2* wp = (const h16x2*)(wlds + gl * 512 + lane * 8);
      float pp = 0.f;
      pp = __builtin_amdgcn_fdot2(wp[0], hh[0], pp, false);
      pp = __builtin_amdgcn_fdot2(wp[1], hh[1], pp, false);
      pp = __builtin_amdgcn_fdot2(wp[2], hh[2], pp, false);
      pp = __builtin_amdgcn_fdot2(wp[3], hh[3], pp, false);
      pp = wred_sum(pp);
      if (lane == 0) ghl[gl] = pp;
    }
    __syncthreads();

    if (tid < 32) {                     // pointwise update (wave 0 lanes 0-31)
      int j = tid;
      float ghr = ghl[j] + bh[j];
      float ghz = ghl[j + 32] + bh[j + 32];
      float ghn = ghl[j + 64] + bh[j + 64];
      float rr = 1.f / (1.f + __expf(-(gir + ghr)));
      float zz = 1.f / (1.f + __expf(-(giz + ghz)));
      float nn = tanhf(gin + rr * ghn);
      float h2v = (1.f - zz) * nn + zz * hprev;
      hprev = h2v;
      if (sidx == 0)   ctx[(dir ? 1536 : 0)    + jg] = h2v;
      if (sidx == 127) ctx[(dir ? 512  : 1024) + jg] = h2v;
      if (sidx < 127) {
        union { float f; unsigned u; } cv; cv.f = h2v;
        u64 pk = ((u64)(unsigned)(sidx + 1) << 32) | (u64)cv.u;
        __hip_atomic_store(&myX[(size_t)sidx * 512 + jg], pk,
                           __ATOMIC_RELAXED, __HIP_MEMORY_SCOPE_AGENT);
      }
    }

    if (sidx < 127) {
      if (wv == 0) {                    // dedicated poll wave: 8 elems/lane
        const unsigned want = (unsigned)(sidx + 1);
        const u64* src = myX + (size_t)sidx * 512;
        const int base = lane * 8;
        u64 v[8];
        unsigned done = 0;
        while (done != 0xFFu) {
          #pragma unroll
          for (int i = 0; i < 8; ++i)
            if (!(done & (1u << i)))
              v[i] = __hip_atomic_load(&src[base + i], __ATOMIC_RELAXED,
                                       __HIP_MEMORY_SCOPE_AGENT);
          #pragma unroll
          for (int i = 0; i < 8; ++i)
            if (!(done & (1u << i)) && (unsigned)(v[i] >> 32) == want)
              done |= 1u << i;
          if (done != 0xFFu) __builtin_amdgcn_s_sleep(1);
        }
        #pragma unroll
        for (int i = 0; i < 8; ++i) {
          union { unsigned u; float f; } cv; cv.u = (unsigned)v[i];
          hfull[base + i] = cv.f;
        }
      }
      __syncthreads();                  // waves 1-3 waited here (no traffic)
      #pragma unroll
      for (int i = 0; i < 4; ++i) {
        hh[i][0] = (_Float16)hfull[lane * 8 + 2 * i];
        hh[i][1] = (_Float16)hfull[lane * 8 + 2 * i + 1];
      }
    }
  }
}

// ---------------------------------------------------------------------------
// small kernels
// ---------------------------------------------------------------------------
__global__ __launch_bounds__(256) void k_softmax1(
    const float* __restrict__ scores, const int* __restrict__ conn, u16* __restrict__ attw)
{
  int p = blockIdx.x * 4 + (threadIdx.x >> 6);
  int lane = threadIdx.x & 63;
  float v0 = scores[(size_t)p * 128 + lane];
  float v1 = scores[(size_t)p * 128 + 64 + lane];
  int m0 = conn[(size_t)p * 128 + lane];
  int m1 = conn[(size_t)p * 128 + 64 + lane];
  float x0 = m0 > 0 ? v0 : -INFINITY;
  float x1 = m1 > 0 ? v1 : -INFINITY;
  float mx = wred_max(fmaxf(x0, x1));
  if (!(mx > -INFINITY)) mx = 0.f;
  float e0 = m0 > 0 ? __expf(v0 - mx) : 0.f;
  float e1 = m1 > 0 ? __expf(v1 - mx) : 0.f;
  float s = wred_sum(e0 + e1);
  float inv = 1.f / (s + 1e-6f);
  attw[(size_t)p * 128 + lane] = f2b(e0 * inv);
  attw[(size_t)p * 128 + 64 + lane] = f2b(e1 * inv);
}

__global__ __launch_bounds__(256) void k_transpose(const u16* __restrict__ in, u16* __restrict__ out)
{
  int idx = blockIdx.x * 256 + threadIdx.x;   // over 128*1024
  int r = idx >> 10, c = idx & 1023;
  out[c * 128 + r] = in[idx];
}

// G[i] = src16[idxs[i]] : bf16 row gather (1024 wide), 4096 rows.
__global__ __launch_bounds__(256) void k_gather(const int* __restrict__ idxs,
    const u16* __restrict__ src, u16* __restrict__ G)
{
  int g = blockIdx.x * 256 + threadIdx.x;    // over 4096*128 16B-chunks
  int row = g >> 7, c16 = g & 127;
  int sidx = idxs[row];
  *(uint4*)(G + (size_t)row * Hn + c16 * 8) =
      *(const uint4*)(src + (size_t)sidx * Hn + c16 * 8);
}

__global__ __launch_bounds__(256) void k_cvec(const float* __restrict__ att1W,
    const float* __restrict__ att1b, const float* __restrict__ ctx, float* __restrict__ cvec)
{
  int i = blockIdx.x * 4 + (threadIdx.x >> 6);
  int lane = threadIdx.x & 63;
  const float* wrow = att1W + (size_t)i * 4096 + 2048 + lane * 32;
  const float* cp = ctx + lane * 32;
  float acc = 0.f;
  #pragma unroll
  for (int k = 0; k < 32; ++k) acc += wrow[k] * cp[k];
  acc = wred_sum(acc);
  if (lane == 0) cvec[i] = acc + att1b[i];
}

// edge scores for relation chunk [cb, cb+rows): edges e=cb+i and e=Rn+cb+i.
__global__ __launch_bounds__(256) void k_edge_s(const int* __restrict__ rcm,
    const u16* __restrict__ U1, const u16* __restrict__ V1c, const float* __restrict__ cvec,
    const float* __restrict__ att2w, const float* __restrict__ att2b,
    float* __restrict__ sval, int cb, int rows)
{
  int idx = blockIdx.x * 4 + (threadIdx.x >> 6);   // [0, 2*rows)
  int lane = threadIdx.x & 63;
  int rL = idx < rows ? idx : idx - rows;
  int e = idx < rows ? cb + idx : Rn + cb + rL;
  int p = rcm[e];
  const u16* u = U1 + (size_t)p * Hn + lane * 16;
  const u16* v = V1c + (size_t)rL * Hn + lane * 16;
  const float* aw = att2w + lane * 16;
  const float* cv = cvec + lane * 16;
  float acc = 0.f;
  #pragma unroll
  for (int i = 0; i < 16; ++i) {
    float x = b2f(u[i]) + b2f(v[i]) + cv[i];
    acc += aw[i] * leaky(x);
  }
  acc = wred_sum(acc);
  if (lane == 0) sval[e] = acc + att2b[0];
}

__global__ __launch_bounds__(256) void k_cnt(const int* __restrict__ rcm, int* __restrict__ cnt)
{
  int e = blockIdx.x * 256 + threadIdx.x;
  if (e < Rn && rcm[e] == rcm[Rn + e]) return;   // duplicate cell: obj copy wins
  atomicAdd(cnt + rcm[e], 1);
}

__global__ __launch_bounds__(256) void k_scan(const int* __restrict__ cnt,
    int* __restrict__ offs, int* __restrict__ cursor)
{
  __shared__ int part[256];
  __shared__ int pscan[256];
  int tid = threadIdx.x;
  int loc[16]; int s = 0;
  #pragma unroll
  for (int i = 0; i < 16; ++i) { loc[i] = cnt[tid * 16 + i]; s += loc[i]; }
  part[tid] = s; __syncthreads();
  if (tid == 0) { int a = 0; for (int i = 0; i < 256; ++i) { pscan[i] = a; a += part[i]; } }
  __syncthreads();
  int base = pscan[tid];
  #pragma unroll
  for (int i = 0; i < 16; ++i) { offs[tid * 16 + i] = base; cursor[tid * 16 + i] = base; base += loc[i]; }
  if (tid == 255) offs[Pn] = base;
}

__global__ __launch_bounds__(256) void k_fill(const int* __restrict__ rcm,
    const float* __restrict__ sval, int* __restrict__ cursor,
    int* __restrict__ er, float* __restrict__ es)
{
  int e = blockIdx.x * 256 + threadIdx.x;
  if (e < Rn && rcm[e] == rcm[Rn + e]) return;
  int slot = atomicAdd(cursor + rcm[e], 1);
  er[slot] = e & (Rn - 1);
  es[slot] = sval[e];
}

__global__ __launch_bounds__(256) void k_att_apply(const int* __restrict__ offs,
    const int* __restrict__ er, const float* __restrict__ es,
    const float* __restrict__ urel, u16* __restrict__ pacc)
{
  int p = blockIdx.x;
  int tid = threadIdx.x;
  int beg = offs[p], end = offs[p + 1];
  float mx = -INFINITY;
  for (int i = beg; i < end; ++i) mx = fmaxf(mx, es[i]);
  float den = 1e-6f;
  for (int i = beg; i < end; ++i) den += __expf(es[i] - mx);
  float inv = 1.f / den;
  float a0 = 0.f, a1 = 0.f, a2 = 0.f, a3 = 0.f;
  int c0 = tid * 4;
  for (int i = beg; i < end; ++i) {
    float wgt = __expf(es[i] - mx) * inv;
    float4 q = *(const float4*)(urel + (size_t)er[i] * Hn + c0);
    a0 += wgt * q.x; a1 += wgt * q.y; a2 += wgt * q.z; a3 += wgt * q.w;
  }
  ushort4 ov; ov.x = f2b(a0); ov.y = f2b(a1); ov.z = f2b(a2); ov.w = f2b(a3);
  *(ushort4*)(pacc + (size_t)p * Hn + c0) = ov;
}

// ---------------------------------------------------------------------------
extern "C" void kernel_launch(void* const* d_in, const int* in_sizes, int n_in,
                              void* d_out, int out_size, void* d_ws, size_t ws_size,
                              hipStream_t stream)
{
  // ALL float tensors are float32 (reference dtype); bf16 only internally.
  const float* word_feat   = (const float*)d_in[0];
  const float* phrase_feat = (const float*)d_in[1];
  const float* rel_feat    = (const float*)d_in[2];
  const float* w_ih_f = (const float*)d_in[3];
  const float* w_hh_f = (const float*)d_in[4];
  const float* b_ih_f = (const float*)d_in[5];
  const float* b_hh_f = (const float*)d_in[6];
  const float* w_ih_b = (const float*)d_in[7];
  const float* w_hh_b = (const float*)d_in[8];
  const float* b_ih_b = (const float*)d_in[9];
  const float* b_hh_b = (const float*)d_in[10];
  const float* w2p_w_W = (const float*)d_in[11];
  const float* w2p_w_b = (const float*)d_in[12];
  const float* w2p_p_W = (const float*)d_in[13];
  const float* w2p_p_b = (const float*)d_in[14];
  const float* w2p_t_W = (const float*)d_in[15];
  const float* w2p_t_b = (const float*)d_in[16];
  const float* rel_W   = (const float*)d_in[17];
  const float* rel_b   = (const float*)d_in[18];
  const float* att1_W  = (const float*)d_in[19];
  const float* att1_b  = (const float*)d_in[20];
  const float* att2_W  = (const float*)d_in[21];
  const float* att2_b  = (const float*)d_in[22];
  const float* r2p_t_W = (const float*)d_in[23];
  const float* r2p_t_b = (const float*)d_in[24];
  const int* rcm  = (const int*)d_in[25];
  const int* conn = (const int*)d_in[26];

  float* out_word = (float*)d_out;
  float* out_phr  = out_word + (size_t)Wn * Hn;   // 4096x1024 f32
  float* out_urel = out_phr + (size_t)Pn * Hn;    // 8192x1024 f32

  // ---- workspace (~44 MB, static layout with phase-disjoint unions) ----
  char* ws = (char*)d_ws;
  size_t off = 0;
  auto alloc = [&](size_t bytes) -> char* {
    char* pptr = ws + off; off += (bytes + 255) & ~(size_t)255; return pptr;
  };
  int*   cnt    = (int*)alloc(Pn * 4);                    // zeroed below
  u64*   X      = (u64*)alloc(2 * 128 * 512 * 8);         // GRU exchange, zeroed
  float* ctx    = (float*)alloc(2048 * 4);
  float* cvec   = (float*)alloc(1024 * 4);
  int*   cursor = (int*)alloc(Pn * 4);
  int*   offs   = (int*)alloc((Pn + 1) * 4);
  int*   er     = (int*)alloc(2 * Rn * 4);
  float* es     = (float*)alloc(2 * Rn * 4);
  float* sval   = (float*)alloc(2 * Rn * 4);
  u16*   wf16   = (u16*)alloc((size_t)Wn * Hn * 2);       // 0.26MB
  u16*   wl     = (u16*)alloc((size_t)Wn * Hn * 2);       // 0.26MB
  u16*   upd16  = (u16*)alloc((size_t)Pn * Hn * 2);       // 8.39MB
  char*  RA     = alloc(16777216);                        // P3 / P5 union
  u16*   W1s    = (u16*)RA;                               // 2.10MB (P3)
  u16*   W2s    = (u16*)(RA + 2097152);                   // 2.10MB (P3)
  u16*   W3s    = (u16*)(RA + 4194304);                   // 2.10MB (P3)
  u16*   G      = (u16*)(RA + 6291456);                   // 8.39MB (P3)
  u16*   rf16c  = (u16*)(RA + 14680064);                  // 2.10MB (P3)
  u16*   pacc   = (u16*)RA;                               // 8.39MB (P5)
  u16*   r2pW16 = (u16*)alloc(2097152);                   // own slot (early cvt)
  u16*   A1p16  = (u16*)alloc(2097152);
  u16*   A1r16  = (u16*)alloc(2097152);
  u16*   U1     = (u16*)alloc((size_t)Pn * Hn * 2);       // 8.39MB
  u16*   urelc  = (u16*)alloc(2097152);
  u16*   V1c    = (u16*)alloc(2097152);

  // ---- d_out f32 regions as early-phase scratch ----
  char* phrB = (char*)out_phr;          // 16.78MB, free until upd write
  float* scores = (float*)phrB;                         // 2.10MB
  u16*   wih16f = (u16*)(phrB + 2097152);               // 3.15MB
  u16*   wih16b = (u16*)(phrB + 5242880);               // 3.15MB
  float* gi_f   = (float*)(phrB + 8388608);             // 0.79MB
  float* gi_b   = (float*)(phrB + 9175040);             // 0.79MB
  char* urlB = (char*)out_urel;         // 33.55MB, free until urel writes
  u16*   pf16   = (u16*)urlB;                           // 8.39MB
  u16*   w2pw16 = (u16*)(urlB + 8388608);               // 2.10MB
  u16*   w2pp16 = (u16*)(urlB + 10485760);              // 2.10MB
  u16*   w2pt16 = (u16*)(urlB + 12582912);              // 2.10MB
  u16*   pl     = (u16*)(urlB + 14680064);              // 8.39MB
  u16*   aw     = (u16*)(urlB + 23068672);              // 8.39MB
  u16*   attw   = (u16*)(urlB + 31457280);              // 1.05MB
  u16*   wfT    = (u16*)(urlB + 32505856);              // 0.26MB

  // zero cnt + X (contiguous)
  (void)hipMemsetAsync(cnt, 0, Pn * 4 + 2 * 128 * 512 * 8, stream);

  dim3 blk(256);

  // P1: word/w_ih cvt + gi GEMMs, then fused {GRU scan || remaining cvts}.
  k_cvt<<<64, blk, 0, stream>>>(word_feat, Hn, wf16);
  k_cvt<<<768, blk, 0, stream>>>(w_ih_f, Hn, wih16f);
  k_cvt<<<768, blk, 0, stream>>>(w_ih_b, Hn, wih16b);
  k_gemm_bt<true, false, true, false, false><<<dim3(12, 1), blk, 0, stream>>>(
      wf16, Hn, wih16f, Hn, gi_f, 1536, b_ih_f, nullptr, 0, nullptr, 1.f, Hn);
  k_gemm_bt<true, false, true, false, false><<<dim3(12, 1), blk, 0, stream>>>(
      wf16, Hn, wih16b, Hn, gi_b, 1536, b_ih_b, nullptr, 0, nullptr, 1.f, Hn);

  CvtTasks T;
  T.t[0] = {phrase_feat,    pf16,   Hn,     Pn * 128};
  T.t[1] = {w2p_w_W,        w2pw16, Hn,     1024 * 128};
  T.t[2] = {w2p_p_W,        w2pp16, Hn,     1024 * 128};
  T.t[3] = {w2p_t_W,        w2pt16, Hn,     1024 * 128};
  T.t[4] = {rel_W,          W1s,    3 * Hn, 1024 * 128};
  T.t[5] = {rel_W + Hn,     W2s,    3 * Hn, 1024 * 128};
  T.t[6] = {rel_W + 2 * Hn, W3s,    3 * Hn, 1024 * 128};
  T.t[7] = {att1_W,         A1p16,  4 * Hn, 1024 * 128};
  T.t[8] = {att1_W + Hn,    A1r16,  4 * Hn, 1024 * 128};
  T.t[9] = {r2p_t_W,        r2pW16, Hn,     1024 * 128};
  T.n = 10;
  k_gru_fused<<<256, blk, 0, stream>>>(
      w_hh_f, w_hh_b, b_hh_f, b_hh_b, gi_f, gi_b, X, ctx, T);

  // P2: word->phrase attention; upd (f32 in out_phr + bf16 copy).
  k_gemm_bt<false, true, true, false, false><<<dim3(8, 1), blk, 0, stream>>>(
      wf16, Hn, w2pw16, Hn, wl, Hn, w2p_w_b, nullptr, 0, nullptr, 1.f, Hn);
  k_gemm_bt<false, true, true, false, false><<<dim3(8, 32), blk, 0, stream>>>(
      pf16, Hn, w2pp16, Hn, pl, Hn, w2p_p_b, nullptr, 0, nullptr, 1.f, Hn);
  k_gemm_bt<true, false, false, false, false><<<dim3(1, 32), blk, 0, stream>>>(
      pl, Hn, wl, Hn, scores, Wn, nullptr, nullptr, 0, nullptr, 0.03125f, Hn);
  k_softmax1<<<Pn / 4, blk, 0, stream>>>(scores, conn, attw);
  k_transpose<<<(Wn * Hn) / 256, blk, 0, stream>>>(wf16, wfT);
  k_gemm_bt<false, false, false, false, false><<<dim3(8, 32), blk, 0, stream>>>(
      attw, Wn, wfT, Wn, aw, Hn, nullptr, nullptr, 0, nullptr, 1.f, Wn);
  k_gemm_bt<true, false, true, true, true><<<dim3(8, 32), blk, 0, stream>>>(
      aw, Hn, w2pt16, Hn, out_phr, Hn, w2p_t_b, phrase_feat, Hn, upd16, 1.f, Hn);

  // P3: urel (f32 in out_urel) = rel_feat@W3' + upd[sub]@W1' + upd[obj]@W2' + b
  for (int cb = 0; cb < Rn; cb += 1024) {
    k_cvt<<<512, blk, 0, stream>>>(rel_feat + (size_t)cb * Hn, Hn, rf16c);
    k_gemm_bt<true, false, true, false, false><<<dim3(8, 8), blk, 0, stream>>>(
        rf16c, Hn, W3s, Hn, out_urel + (size_t)cb * Hn, Hn, rel_b, nullptr, 0,
        nullptr, 1.f, Hn);
  }
  for (int h = 0; h < 2; ++h) {
    float* Ch = out_urel + (size_t)h * 4096 * Hn;
    k_gather<<<2048, blk, 0, stream>>>(rcm + h * 4096, upd16, G);
    k_gemm_bt<true, false, false, true, false><<<dim3(8, 32), blk, 0, stream>>>(
        G, Hn, W1s, Hn, Ch, Hn, nullptr, Ch, Hn, nullptr, 1.f, Hn);
    k_gather<<<2048, blk, 0, stream>>>(rcm + Rn + h * 4096, upd16, G);
    k_gemm_bt<true, false, false, true, false><<<dim3(8, 32), blk, 0, stream>>>(
        G, Hn, W2s, Hn, Ch, Hn, nullptr, Ch, Hn, nullptr, 1.f, Hn);
  }

  // P4: edge scores s = att2 . leaky(U1[p] + V1[r] + cvec)
  k_gemm_bt<false, false, false, false, false><<<dim3(8, 32), blk, 0, stream>>>(
      upd16, Hn, A1p16, Hn, U1, Hn, nullptr, nullptr, 0, nullptr, 1.f, Hn);
  k_cvec<<<256, blk, 0, stream>>>(att1_W, att1_b, ctx, cvec);
  for (int cb = 0; cb < Rn; cb += 1024) {
    k_cvt<<<512, blk, 0, stream>>>(out_urel + (size_t)cb * Hn, Hn, urelc);
    k_gemm_bt<false, false, false, false, false><<<dim3(8, 8), blk, 0, stream>>>(
        urelc, Hn, A1r16, Hn, V1c, Hn, nullptr, nullptr, 0, nullptr, 1.f, Hn);
    k_edge_s<<<512, blk, 0, stream>>>(rcm, U1, V1c, cvec, att2_W, att2_b, sval, cb, 1024);
  }

  // P5: CSR + masked softmax + att@urel; final residual GEMM in-place.
  k_cnt<<<(2 * Rn) / 256, blk, 0, stream>>>(rcm, cnt);
  k_scan<<<1, blk, 0, stream>>>(cnt, offs, cursor);
  k_fill<<<(2 * Rn) / 256, blk, 0, stream>>>(rcm, sval, cursor, er, es);
  k_att_apply<<<Pn, blk, 0, stream>>>(offs, er, es, out_urel, pacc);
  k_gemm_bt<true, false, true, true, false><<<dim3(8, 32), blk, 0, stream>>>(
      pacc, Hn, r2pW16, Hn, out_phr, Hn, r2p_t_b, out_phr, Hn, nullptr, 1.f, Hn);

  // word_feat passthrough (f32)
  (void)hipMemcpyAsync(out_word, word_feat, (size_t)Wn * Hn * 4,
                       hipMemcpyDeviceToDevice, stream);
}

// Round 7
// 1643.021 us; speedup vs baseline: 1.0528x; 1.0528x over previous
//
#include <hip/hip_runtime.h>

#define DEV __device__ __forceinline__

typedef short s16x8 __attribute__((ext_vector_type(8)));
typedef float f32x4 __attribute__((ext_vector_type(4)));
typedef _Float16 h16x2 __attribute__((ext_vector_type(2)));
typedef unsigned short u16;
typedef unsigned long long u64;

constexpr int Wn = 128;    // words
constexpr int Pn = 4096;   // phrases
constexpr int Rn = 8192;   // relations
constexpr int Hn = 1024;   // hidden

DEV float b2f(u16 u) { union { unsigned i; float f; } x; x.i = (unsigned)u << 16; return x.f; }
DEV u16 f2b(float f) {
  union { float f; unsigned i; } x; x.f = f;
  unsigned r = x.i + 0x7FFF + ((x.i >> 16) & 1);   // RNE
  return (u16)(r >> 16);
}
DEV float leaky(float x) { return x >= 0.f ? x : 0.01f * x; }

DEV void load_lds16(const void* g, void* l) {
  __builtin_amdgcn_global_load_lds(
      (const __attribute__((address_space(1))) void*)g,
      (__attribute__((address_space(3))) void*)l, 16, 0, 0);
}

DEV float wred_sum(float v) {
  #pragma unroll
  for (int m = 1; m < 64; m <<= 1) v += __shfl_xor(v, m, 64);
  return v;
}
DEV float wred_max(float v) {
  #pragma unroll
  for (int m = 1; m < 64; m <<= 1) v = fmaxf(v, __shfl_xor(v, m, 64));
  return v;
}

// ---------------------------------------------------------------------------
// One 128x128 output tile of C = epilogue(A[M,K] @ B[N,K]^T), bf16 inputs.
// Uses the calling block's 256 threads and the supplied 32KB LDS buffer.
// ---------------------------------------------------------------------------
template<bool OUTF32, bool ACT, bool BIAS, bool RES, bool DUAL>
DEV void gemm_tile(char* sm,
    const u16* __restrict__ A, int lda,
    const u16* __restrict__ B, int ldb,
    void* Cp, int ldc,
    const float* __restrict__ bias,
    const float* res, int ldr,
    u16* C16, float alpha, int K, int m0, int n0)
{
  char* As = sm;
  char* Bs = sm + 16384;
  const int tid = threadIdx.x;
  const int lane = tid & 63, w = tid >> 6;
  const int wr = (w >> 1) * 64, wc = (w & 1) * 64;
  const int r_lo = lane & 15, kq = lane >> 4;

  __syncthreads();                       // LDS reuse across tiles

  f32x4 acc[4][4];
  #pragma unroll
  for (int i = 0; i < 4; ++i)
    #pragma unroll
    for (int j = 0; j < 4; ++j) acc[i][j] = (f32x4){0.f, 0.f, 0.f, 0.f};

  for (int kt = 0; kt < K; kt += 64) {
    if (kt) __syncthreads();
    #pragma unroll
    for (int i = 0; i < 4; ++i) {        // stage A (4 x 4KB)
      int f = i * 4096 + tid * 16;
      int row = f >> 7, colb = f & 127;
      int scol = colb ^ ((row & 7) << 4);
      const char* src = (const char*)(A + (size_t)(m0 + row) * lda + kt) + scol;
      load_lds16(src, As + i * 4096 + w * 1024);
    }
    #pragma unroll
    for (int i = 0; i < 4; ++i) {        // stage B
      int f = i * 4096 + tid * 16;
      int row = f >> 7, colb = f & 127;
      int scol = colb ^ ((row & 7) << 4);
      const char* src = (const char*)(B + (size_t)(n0 + row) * ldb + kt) + scol;
      load_lds16(src, Bs + i * 4096 + w * 1024);
    }
    __syncthreads();
    #pragma unroll
    for (int ks = 0; ks < 2; ++ks) {
      s16x8 af[4], bfr[4];
      const int kb = ks * 64 + kq * 16;
      #pragma unroll
      for (int mi = 0; mi < 4; ++mi) {
        int row = wr + mi * 16 + r_lo;
        af[mi] = *(const s16x8*)(As + row * 128 + (kb ^ ((row & 7) << 4)));
      }
      #pragma unroll
      for (int ni = 0; ni < 4; ++ni) {
        int row = wc + ni * 16 + r_lo;
        bfr[ni] = *(const s16x8*)(Bs + row * 128 + (kb ^ ((row & 7) << 4)));
      }
      #pragma unroll
      for (int mi = 0; mi < 4; ++mi)
        #pragma unroll
        for (int ni = 0; ni < 4; ++ni)
          acc[mi][ni] = __builtin_amdgcn_mfma_f32_16x16x32_bf16(af[mi], bfr[ni], acc[mi][ni], 0, 0, 0);
    }
  }

  #pragma unroll
  for (int mi = 0; mi < 4; ++mi) {
    #pragma unroll
    for (int ni = 0; ni < 4; ++ni) {
      #pragma unroll
      for (int j = 0; j < 4; ++j) {
        int r = m0 + wr + mi * 16 + kq * 4 + j;
        int c = n0 + wc + ni * 16 + r_lo;
        float v = acc[mi][ni][j] * alpha;
        if (BIAS) v += bias[c];
        if (RES)  v += res[(size_t)r * ldr + c];
        if (ACT)  v = leaky(v);
        if (OUTF32) ((float*)Cp)[(size_t)r * ldc + c] = v;
        else        ((u16*)Cp)[(size_t)r * ldc + c] = f2b(v);
        if (DUAL)   C16[(size_t)r * ldc + c] = f2b(v);
      }
    }
  }
}

template<bool OUTF32, bool ACT, bool BIAS, bool RES, bool DUAL>
__global__ __launch_bounds__(256) void k_gemm_bt(
    const u16* __restrict__ A, int lda, const u16* __restrict__ B, int ldb,
    void* Cp, int ldc, const float* __restrict__ bias,
    const float* res, int ldr, u16* C16, float alpha, int K)
{
  __shared__ __align__(16) char sm[32768];
  gemm_tile<OUTF32, ACT, BIAS, RES, DUAL>(sm, A, lda, B, ldb, Cp, ldc, bias,
      res, ldr, C16, alpha, K, blockIdx.y * 128, blockIdx.x * 128);
}

// ---------------------------------------------------------------------------
// MEGAKERNEL: blocks 0..31 = bidirectional GRU scan (tagged-atomic exchange);
// blocks 32..255 = worker pipeline for all ctx-independent work, separated by
// flag barriers (release add / acquire spin on tid 0 + __syncthreads).
// ---------------------------------------------------------------------------
struct MKArgs {
  const float *w_hh_f, *w_hh_b, *b_hh_f, *b_hh_b;
  const float *word_feat, *phrase_feat, *rel_feat;
  const float *w_ih_f, *b_ih_f, *w_ih_b, *b_ih_b;
  const float *w2p_w_W, *w2p_w_b, *w2p_p_W, *w2p_p_b, *w2p_t_W, *w2p_t_b;
  const float *rel_W, *rel_b, *att1_W, *r2p_t_W;
  const int *rcm, *conn;
  u64* X; float* ctx; int* pc; int* cnt2; int* offs; int* cursor;
  float *gi_f, *gi_b, *scores;
  u16 *wf16, *wih16f, *wih16b, *wl, *upd16;
  u16 *W1s, *W2s, *W3s, *G, *V1f, *A1p16, *A1r16, *U1, *CB, *r2pW16;
  u16 *pf16, *w2pw16, *w2pp16, *w2pt16, *pl, *aw, *attw, *wfT;
  float *out_phr, *out_urel;
};

__global__ __launch_bounds__(256) void k_mega(MKArgs a)
{
  __shared__ __align__(16) u16 wlds[96 * 512];   // GRU weights (96KB)
  __shared__ float bh[96];
  __shared__ float hfull[512];
  __shared__ float ghl[96];
  __shared__ __align__(16) char sm[32768];       // worker GEMM LDS
  __shared__ int sscan[512];                     // worker scan

  const int bid = blockIdx.x;
  const int tid = threadIdx.x;
  const int NW = (int)gridDim.x - 32;

  if (bid >= 32) {
    // =================== WORKER PATH ===================
    const int bc = bid - 32, nb = NW;
    int bar = 0;
    auto wbarrier = [&]() {
      __syncthreads();
      if (tid == 0) {
        __hip_atomic_fetch_add(&a.pc[bar], 1, __ATOMIC_ACQ_REL, __HIP_MEMORY_SCOPE_AGENT);
        while (__hip_atomic_load(&a.pc[bar], __ATOMIC_ACQUIRE, __HIP_MEMORY_SCOPE_AGENT) < NW)
          __builtin_amdgcn_s_sleep(4);
      }
      __syncthreads();
      ++bar;
    };
    auto cvt_task = [&](const float* src, int sld, u16* dst, int units) {
      for (int u = bc * 256 + tid; u < units; u += nb * 256) {
        int row = u >> 7, c = (u & 127) * 8;
        const float* s = src + (size_t)row * sld + c;
        float4 va = *(const float4*)s;
        float4 vb = *(const float4*)(s + 4);
        ushort4 lo = {f2b(va.x), f2b(va.y), f2b(va.z), f2b(va.w)};
        ushort4 hi = {f2b(vb.x), f2b(vb.y), f2b(vb.z), f2b(vb.w)};
        *(ushort4*)(dst + (size_t)row * 1024 + c) = lo;
        *(ushort4*)(dst + (size_t)row * 1024 + c + 4) = hi;
      }
    };
    auto gather_task = [&](const int* idxs, const u16* src, u16* dst) {
      for (int u = bc * 256 + tid; u < 4096 * 128; u += nb * 256) {
        int row = u >> 7, c16 = u & 127;
        int sidx = idxs[row];
        *(uint4*)(dst + (size_t)row * Hn + c16 * 8) =
            *(const uint4*)(src + (size_t)sidx * Hn + c16 * 8);
      }
    };

    // Ph0: wf16 + wih16 conversions
    cvt_task(a.word_feat, Hn, a.wf16, Wn * 128);
    cvt_task(a.w_ih_f, Hn, a.wih16f, 1536 * 128);
    cvt_task(a.w_ih_b, Hn, a.wih16b, 1536 * 128);
    wbarrier();                                   // bar 0
    // Ph1: gi GEMMs (releases GRU at bar index 1)
    for (int u = bc; u < 24; u += nb) {
      const u16* Bm = u < 12 ? a.wih16f : a.wih16b;
      float* Cm = u < 12 ? a.gi_f : a.gi_b;
      const float* bm = u < 12 ? a.b_ih_f : a.b_ih_b;
      gemm_tile<true, false, true, false, false>(sm, a.wf16, Hn, Bm, Hn, Cm,
          1536, bm, nullptr, 0, nullptr, 1.f, Hn, 0, (u % 12) * 128);
    }
    wbarrier();                                   // bar 1 (GRU gate)
    // Ph2: bulk conversions
    cvt_task(a.phrase_feat, Hn, a.pf16, Pn * 128);
    cvt_task(a.w2p_w_W, Hn, a.w2pw16, 1024 * 128);
    cvt_task(a.w2p_p_W, Hn, a.w2pp16, 1024 * 128);
    cvt_task(a.w2p_t_W, Hn, a.w2pt16, 1024 * 128);
    cvt_task(a.rel_W, 3 * Hn, a.W1s, 1024 * 128);
    cvt_task(a.rel_W + Hn, 3 * Hn, a.W2s, 1024 * 128);
    cvt_task(a.rel_W + 2 * Hn, 3 * Hn, a.W3s, 1024 * 128);
    cvt_task(a.att1_W, 4 * Hn, a.A1p16, 1024 * 128);
    cvt_task(a.att1_W + Hn, 4 * Hn, a.A1r16, 1024 * 128);
    wbarrier();                                   // bar 2
    // Ph3: wl (8 tiles) + pl (256 tiles)
    for (int u = bc; u < 264; u += nb) {
      if (u < 8)
        gemm_tile<false, true, true, false, false>(sm, a.wf16, Hn, a.w2pw16, Hn,
            a.wl, Hn, a.w2p_w_b, nullptr, 0, nullptr, 1.f, Hn, 0, u * 128);
      else {
        int t = u - 8;
        gemm_tile<false, true, true, false, false>(sm, a.pf16, Hn, a.w2pp16, Hn,
            a.pl, Hn, a.w2p_p_b, nullptr, 0, nullptr, 1.f, Hn,
            (t >> 3) * 128, (t & 7) * 128);
      }
    }
    wbarrier();                                   // bar 3
    // Ph4: scores (32 tiles) + wfT transpose (512 chunk units)
    for (int u = bc; u < 32 + 512; u += nb) {
      if (u < 32)
        gemm_tile<true, false, false, false, false>(sm, a.pl, Hn, a.wl, Hn,
            a.scores, Wn, nullptr, nullptr, 0, nullptr, 0.03125f, Hn, u * 128, 0);
      else {
        int idx = (u - 32) * 256 + tid;           // over 128*1024
        int r = idx >> 10, c = idx & 1023;
        a.wfT[c * 128 + r] = a.wf16[idx];
      }
    }
    wbarrier();                                   // bar 4
    // Ph5: masked softmax over words (1024 units x 4 phrases)
    for (int u = bc; u < 1024; u += nb) {
      int p = u * 4 + (tid >> 6);
      int lane = tid & 63;
      float v0 = a.scores[(size_t)p * 128 + lane];
      float v1 = a.scores[(size_t)p * 128 + 64 + lane];
      int m0 = a.conn[(size_t)p * 128 + lane];
      int m1 = a.conn[(size_t)p * 128 + 64 + lane];
      float x0 = m0 > 0 ? v0 : -INFINITY;
      float x1 = m1 > 0 ? v1 : -INFINITY;
      float mx = wred_max(fmaxf(x0, x1));
      if (!(mx > -INFINITY)) mx = 0.f;
      float e0 = m0 > 0 ? __expf(v0 - mx) : 0.f;
      float e1 = m1 > 0 ? __expf(v1 - mx) : 0.f;
      float s = wred_sum(e0 + e1);
      float inv = 1.f / (s + 1e-6f);
      a.attw[(size_t)p * 128 + lane] = f2b(e0 * inv);
      a.attw[(size_t)p * 128 + 64 + lane] = f2b(e1 * inv);
    }
    wbarrier();                                   // bar 5
    // Ph6: aw = attw @ wfT^T (256 tiles, K=128)
    for (int u = bc; u < 256; u += nb)
      gemm_tile<false, false, false, false, false>(sm, a.attw, Wn, a.wfT, Wn,
          a.aw, Hn, nullptr, nullptr, 0, nullptr, 1.f, Wn, (u >> 3) * 128, (u & 7) * 128);
    wbarrier();                                   // bar 6
    // Ph7: upd = phrase + aw @ w2p_t^T + b (dual write f32 + bf16)
    for (int u = bc; u < 256; u += nb)
      gemm_tile<true, false, true, true, true>(sm, a.aw, Hn, a.w2pt16, Hn,
          a.out_phr, Hn, a.w2p_t_b, a.phrase_feat, Hn, a.upd16, 1.f, Hn,
          (u >> 3) * 128, (u & 7) * 128);
    wbarrier();                                   // bar 7
    // Ph8: cvt rel_feat lower half -> G
    cvt_task(a.rel_feat, Hn, a.G, 4096 * 128);
    wbarrier();                                   // bar 8
    // Ph9: RF3 lower (256 tiles) + U1 (256 tiles)
    for (int u = bc; u < 512; u += nb) {
      if (u < 256)
        gemm_tile<true, false, true, false, false>(sm, a.G, Hn, a.W3s, Hn,
            a.out_urel, Hn, a.rel_b, nullptr, 0, nullptr, 1.f, Hn,
            (u >> 3) * 128, (u & 7) * 128);
      else {
        int t = u - 256;
        gemm_tile<false, false, false, false, false>(sm, a.upd16, Hn, a.A1p16, Hn,
            a.U1, Hn, nullptr, nullptr, 0, nullptr, 1.f, Hn,
            (t >> 3) * 128, (t & 7) * 128);
      }
    }
    wbarrier();                                   // bar 9
    // Ph10: cvt rel_feat upper half -> G
    cvt_task(a.rel_feat + (size_t)4096 * Hn, Hn, a.G, 4096 * 128);
    wbarrier();                                   // bar 10
    // Ph11: RF3 upper (256 tiles)
    for (int u = bc; u < 256; u += nb)
      gemm_tile<true, false, true, false, false>(sm, a.G, Hn, a.W3s, Hn,
          a.out_urel + (size_t)4096 * Hn, Hn, a.rel_b, nullptr, 0, nullptr,
          1.f, Hn, (u >> 3) * 128, (u & 7) * 128);
    wbarrier();                                   // bar 11
    // Ph12..19: four {gather -> accumulate-GEMM} rounds
    for (int h = 0; h < 2; ++h) {
      float* Ch = a.out_urel + (size_t)h * 4096 * Hn;
      const u16* Wm[2] = {a.W1s, a.W2s};
      const int* ix[2] = {a.rcm + h * 4096, a.rcm + Rn + h * 4096};
      for (int s = 0; s < 2; ++s) {
        gather_task(ix[s], a.upd16, a.G);
        wbarrier();
        for (int u = bc; u < 256; u += nb)
          gemm_tile<true, false, false, true, false>(sm, a.G, Hn, Wm[s], Hn,
              Ch, Hn, nullptr, Ch, Hn, nullptr, 1.f, Hn,
              (u >> 3) * 128, (u & 7) * 128);
        wbarrier();
      }
    }                                             // bars 12..19
    // Ph20..27: V1 = urel16 @ A1r^T in 4 chunks of 2048 rows
    for (int cb = 0; cb < Rn; cb += 2048) {
      cvt_task(a.out_urel + (size_t)cb * Hn, Hn, a.CB, 2048 * 128);
      wbarrier();
      for (int u = bc; u < 128; u += nb)
        gemm_tile<false, false, false, false, false>(sm, a.CB, Hn, a.A1r16, Hn,
            a.V1f + (size_t)cb * Hn, Hn, nullptr, nullptr, 0, nullptr, 1.f, Hn,
            (u >> 3) * 128, (u & 7) * 128);
      wbarrier();
    }                                             // bars 20..27
    // Ph28: cnt (edge histogram) + r2pW16 cvt (into CB slot)
    for (int u = bc * 256 + tid; u < 2 * Rn; u += nb * 256) {
      int e = u;
      if (e < Rn && a.rcm[e] == a.rcm[Rn + e]) continue;
      atomicAdd(a.cnt2 + a.rcm[e], 1);
    }
    cvt_task(a.r2p_t_W, Hn, a.r2pW16, 1024 * 128);
    wbarrier();                                   // bar 28
    // Ph29: scan (first worker block only)
    if (bc == 0) {
      int* part = sscan;
      int* pscan = sscan + 256;
      int loc[16]; int s = 0;
      #pragma unroll
      for (int i = 0; i < 16; ++i) { loc[i] = a.cnt2[tid * 16 + i]; s += loc[i]; }
      part[tid] = s; __syncthreads();
      if (tid == 0) { int acc = 0; for (int i = 0; i < 256; ++i) { pscan[i] = acc; acc += part[i]; } }
      __syncthreads();
      int base = pscan[tid];
      #pragma unroll
      for (int i = 0; i < 16; ++i) {
        a.offs[tid * 16 + i] = base; a.cursor[tid * 16 + i] = base; base += loc[i];
      }
      if (tid == 255) a.offs[Pn] = base;
    }
    return;
  }

  // =================== GRU PATH (blocks 0..31) ===================
  const int dir = bid >> 4;
  const int b   = bid & 15;
  const int lane = tid & 63, wv = tid >> 6;

  const float* w_hh = dir ? a.w_hh_b : a.w_hh_f;
  const float* b_hh = dir ? a.b_hh_b : a.b_hh_f;
  const float* gi = dir ? a.gi_b : a.gi_f;
  u64* myX = a.X + (size_t)dir * 128 * 512;

  for (int idx = tid; idx < 96 * 128; idx += 256) {   // weights f32 -> f16 LDS
    int gl = idx >> 7;
    int kc = (idx & 127) << 2;
    int g = 32 * b + (gl & 31) + ((gl >> 5) << 9);
    float4 wv4 = *(const float4*)(w_hh + (size_t)g * 512 + kc);
    u16 dst[4];
    _Float16 h0 = (_Float16)wv4.x; __builtin_memcpy(&dst[0], &h0, 2);
    _Float16 h1 = (_Float16)wv4.y; __builtin_memcpy(&dst[1], &h1, 2);
    _Float16 h2 = (_Float16)wv4.z; __builtin_memcpy(&dst[2], &h2, 2);
    _Float16 h3 = (_Float16)wv4.w; __builtin_memcpy(&dst[3], &h3, 2);
    *(uint2*)(wlds + gl * 512 + kc) = *(uint2*)dst;
  }
  if (tid < 96) {
    int g = 32 * b + (tid & 31) + ((tid >> 5) << 9);
    bh[tid] = b_hh[g];
  }
  // wait for gi (worker barrier index 1)
  if (tid == 0) {
    while (__hip_atomic_load(&a.pc[1], __ATOMIC_ACQUIRE, __HIP_MEMORY_SCOPE_AGENT) < NW)
      __builtin_amdgcn_s_sleep(16);
  }
  __syncthreads();

  h16x2 hh[4];
  #pragma unroll
  for (int i = 0; i < 4; ++i) { hh[i][0] = (_Float16)0.f; hh[i][1] = (_Float16)0.f; }
  float hprev = 0.f;
  const int jg = 32 * b + tid;          // valid for tid<32

  for (int sidx = 0; sidx < 128; ++sidx) {
    const int t = dir ? (127 - sidx) : sidx;

    float gir = 0.f, giz = 0.f, gin = 0.f;
    if (tid < 32) {
      gir = gi[t * 1536 + jg];
      giz = gi[t * 1536 + 512 + jg];
      gin = gi[t * 1536 + 1024 + jg];
    }

    for (int gg = 0; gg < 24; ++gg) {
      int gl = wv * 24 + gg;
      const h16x2* wp = (const h16x2*)(wlds + gl * 512 + lane * 8);
      float pp = 0.f;
      pp = __builtin_amdgcn_fdot2(wp[0], hh[0], pp, false);
      pp = __builtin_amdgcn_fdot2(wp[1], hh[1], pp, false);
      pp = __builtin_amdgcn_fdot2(wp[2], hh[2], pp, false);
      pp = __builtin_amdgcn_fdot2(wp[3], hh[3], pp, false);
      pp = wred_sum(pp);
      if (lane == 0) ghl[gl] = pp;
    }
    __syncthreads();

    if (tid < 32) {
      int j = tid;
      float ghr = ghl[j] + bh[j];
      float ghz = ghl[j + 32] + bh[j + 32];
      float ghn = ghl[j + 64] + bh[j + 64];
      float rr = 1.f / (1.f + __expf(-(gir + ghr)));
      float zz = 1.f / (1.f + __expf(-(giz + ghz)));
      float nn = tanhf(gin + rr * ghn);
      float h2v = (1.f - zz) * nn + zz * hprev;
      hprev = h2v;
      if (sidx == 0)   a.ctx[(dir ? 1536 : 0)    + jg] = h2v;
      if (sidx == 127) a.ctx[(dir ? 512  : 1024) + jg] = h2v;
      if (sidx < 127) {
        union { float f; unsigned u; } cv; cv.f = h2v;
        u64 pk = ((u64)(unsigned)(sidx + 1) << 32) | (u64)cv.u;
        __hip_atomic_store(&myX[(size_t)sidx * 512 + jg], pk,
                           __ATOMIC_RELAXED, __HIP_MEMORY_SCOPE_AGENT);
      }
    }

    if (sidx < 127) {
      if (wv == 0) {                    // dedicated poll wave
        const unsigned want = (unsigned)(sidx + 1);
        const u64* src = myX + (size_t)sidx * 512;
        const int base = lane * 8;
        u64 v[8];
        unsigned done = 0;
        while (done != 0xFFu) {
          #pragma unroll
          for (int i = 0; i < 8; ++i)
            if (!(done & (1u << i)))
              v[i] = __hip_atomic_load(&src[base + i], __ATOMIC_RELAXED,
                                       __HIP_MEMORY_SCOPE_AGENT);
          #pragma unroll
          for (int i = 0; i < 8; ++i)
            if (!(done & (1u << i)) && (unsigned)(v[i] >> 32) == want)
              done |= 1u << i;
          if (done != 0xFFu) __builtin_amdgcn_s_sleep(1);
        }
        #pragma unroll
        for (int i = 0; i < 8; ++i) {
          union { unsigned u; float f; } cv; cv.u = (unsigned)v[i];
          hfull[base + i] = cv.f;
        }
      }
      __syncthreads();
      #pragma unroll
      for (int i = 0; i < 4; ++i) {
        hh[i][0] = (_Float16)hfull[lane * 8 + 2 * i];
        hh[i][1] = (_Float16)hfull[lane * 8 + 2 * i + 1];
      }
    }
  }
}

// ---------------------------------------------------------------------------
// tail kernels (ctx-dependent)
// ---------------------------------------------------------------------------
__global__ __launch_bounds__(256) void k_cvec(const float* __restrict__ att1W,
    const float* __restrict__ att1b, const float* __restrict__ ctx, float* __restrict__ cvec)
{
  int i = blockIdx.x * 4 + (threadIdx.x >> 6);
  int lane = threadIdx.x & 63;
  const float* wrow = att1W + (size_t)i * 4096 + 2048 + lane * 32;
  const float* cp = ctx + lane * 32;
  float acc = 0.f;
  #pragma unroll
  for (int k = 0; k < 32; ++k) acc += wrow[k] * cp[k];
  acc = wred_sum(acc);
  if (lane == 0) cvec[i] = acc + att1b[i];
}

__global__ __launch_bounds__(256) void k_edge_s(const int* __restrict__ rcm,
    const u16* __restrict__ U1, const u16* __restrict__ V1, const float* __restrict__ cvec,
    const float* __restrict__ att2w, const float* __restrict__ att2b,
    float* __restrict__ sval)
{
  int idx = blockIdx.x * 4 + (threadIdx.x >> 6);   // [0, 2*Rn)
  int lane = threadIdx.x & 63;
  int rL = idx < Rn ? idx : idx - Rn;
  int e = idx;
  int p = rcm[e];
  const u16* u = U1 + (size_t)p * Hn + lane * 16;
  const u16* v = V1 + (size_t)rL * Hn + lane * 16;
  const float* aw = att2w + lane * 16;
  const float* cv = cvec + lane * 16;
  float acc = 0.f;
  #pragma unroll
  for (int i = 0; i < 16; ++i) {
    float x = b2f(u[i]) + b2f(v[i]) + cv[i];
    acc += aw[i] * leaky(x);
  }
  acc = wred_sum(acc);
  if (lane == 0) sval[e] = acc + att2b[0];
}

__global__ __launch_bounds__(256) void k_fill(const int* __restrict__ rcm,
    const float* __restrict__ sval, int* __restrict__ cursor,
    int* __restrict__ er, float* __restrict__ es)
{
  int e = blockIdx.x * 256 + threadIdx.x;
  if (e < Rn && rcm[e] == rcm[Rn + e]) return;
  int slot = atomicAdd(cursor + rcm[e], 1);
  er[slot] = e & (Rn - 1);
  es[slot] = sval[e];
}

__global__ __launch_bounds__(256) void k_att_apply(const int* __restrict__ offs,
    const int* __restrict__ er, const float* __restrict__ es,
    const float* __restrict__ urel, u16* __restrict__ pacc)
{
  int p = blockIdx.x;
  int tid = threadIdx.x;
  int beg = offs[p], end = offs[p + 1];
  float mx = -INFINITY;
  for (int i = beg; i < end; ++i) mx = fmaxf(mx, es[i]);
  float den = 1e-6f;
  for (int i = beg; i < end; ++i) den += __expf(es[i] - mx);
  float inv = 1.f / den;
  float a0 = 0.f, a1 = 0.f, a2 = 0.f, a3 = 0.f;
  int c0 = tid * 4;
  for (int i = beg; i < end; ++i) {
    float wgt = __expf(es[i] - mx) * inv;
    float4 q = *(const float4*)(urel + (size_t)er[i] * Hn + c0);
    a0 += wgt * q.x; a1 += wgt * q.y; a2 += wgt * q.z; a3 += wgt * q.w;
  }
  ushort4 ov; ov.x = f2b(a0); ov.y = f2b(a1); ov.z = f2b(a2); ov.w = f2b(a3);
  *(ushort4*)(pacc + (size_t)p * Hn + c0) = ov;
}

// ---------------------------------------------------------------------------
extern "C" void kernel_launch(void* const* d_in, const int* in_sizes, int n_in,
                              void* d_out, int out_size, void* d_ws, size_t ws_size,
                              hipStream_t stream)
{
  const float* word_feat   = (const float*)d_in[0];
  const float* phrase_feat = (const float*)d_in[1];
  const float* rel_feat    = (const float*)d_in[2];
  const float* w_ih_f = (const float*)d_in[3];
  const float* w_hh_f = (const float*)d_in[4];
  const float* b_ih_f = (const float*)d_in[5];
  const float* b_hh_f = (const float*)d_in[6];
  const float* w_ih_b = (const float*)d_in[7];
  const float* w_hh_b = (const float*)d_in[8];
  const float* b_ih_b = (const float*)d_in[9];
  const float* b_hh_b = (const float*)d_in[10];
  const float* w2p_w_W = (const float*)d_in[11];
  const float* w2p_w_b = (const float*)d_in[12];
  const float* w2p_p_W = (const float*)d_in[13];
  const float* w2p_p_b = (const float*)d_in[14];
  const float* w2p_t_W = (const float*)d_in[15];
  const float* w2p_t_b = (const float*)d_in[16];
  const float* rel_W   = (const float*)d_in[17];
  const float* rel_b   = (const float*)d_in[18];
  const float* att1_W  = (const float*)d_in[19];
  const float* att1_b  = (const float*)d_in[20];
  const float* att2_W  = (const float*)d_in[21];
  const float* att2_b  = (const float*)d_in[22];
  const float* r2p_t_W = (const float*)d_in[23];
  const float* r2p_t_b = (const float*)d_in[24];
  const int* rcm  = (const int*)d_in[25];
  const int* conn = (const int*)d_in[26];

  float* out_word = (float*)d_out;
  float* out_phr  = out_word + (size_t)Wn * Hn;   // 4096x1024 f32
  float* out_urel = out_phr + (size_t)Pn * Hn;    // 8192x1024 f32

  // ---- workspace (~44.8 MB) ----
  char* ws = (char*)d_ws;
  size_t off = 0;
  auto alloc = [&](size_t bytes) -> char* {
    char* pptr = ws + off; off += (bytes + 255) & ~(size_t)255; return pptr;
  };
  int*   cnt2   = (int*)alloc(Pn * 4);                    // } zeroed
  int*   pc     = (int*)alloc(64 * 4);                    // } together
  u64*   X      = (u64*)alloc(2 * 128 * 512 * 8);         // }
  size_t zlen   = (size_t)((char*)(X + 2 * 128 * 512) - (char*)cnt2);
  float* ctx    = (float*)alloc(2048 * 4);
  float* cvec   = (float*)alloc(1024 * 4);
  int*   cursor = (int*)alloc(Pn * 4);
  int*   offs   = (int*)alloc((Pn + 1) * 4);
  int*   er     = (int*)alloc(2 * Rn * 4);
  float* es     = (float*)alloc(2 * Rn * 4);
  float* sval   = (float*)alloc(2 * Rn * 4);
  float* gi_f   = (float*)alloc(128 * 1536 * 4);
  float* gi_b   = (float*)alloc(128 * 1536 * 4);
  u16*   wf16   = (u16*)alloc((size_t)Wn * Hn * 2);
  u16*   wl     = (u16*)alloc((size_t)Wn * Hn * 2);
  u16*   upd16  = (u16*)alloc((size_t)Pn * Hn * 2);       // later: pacc
  char*  RA     = alloc(16777216);                        // W1s/W2s/W3s/G -> V1
  u16*   W1s    = (u16*)RA;
  u16*   W2s    = (u16*)(RA + 2097152);
  u16*   W3s    = (u16*)(RA + 4194304);
  u16*   G      = (u16*)(RA + 6291456);                   // 8.39MB
  u16*   V1f    = (u16*)RA;                               // full 16.78MB (late)
  u16*   A1p16  = (u16*)alloc(2097152);
  u16*   A1r16  = (u16*)alloc(2097152);
  u16*   U1     = (u16*)alloc((size_t)Pn * Hn * 2);
  char*  CBr    = alloc(4194304);                         // urel cvt chunk
  u16*   CB     = (u16*)CBr;
  u16*   r2pW16 = (u16*)CBr;                              // (after CB dead)
  u16*   pacc   = upd16;                                  // after gathers done

  // ---- d_out regions as early scratch ----
  char* phrB = (char*)out_phr;
  u16*   wih16f = (u16*)phrB;                           // 3.15MB
  u16*   wih16b = (u16*)(phrB + 3145728);               // 3.15MB
  float* scores = (float*)(phrB + 6291456);             // 2.10MB
  char* urlB = (char*)out_urel;
  u16*   pf16   = (u16*)urlB;                           // 8.39MB
  u16*   w2pw16 = (u16*)(urlB + 8388608);
  u16*   w2pp16 = (u16*)(urlB + 10485760);
  u16*   w2pt16 = (u16*)(urlB + 12582912);
  u16*   pl     = (u16*)(urlB + 14680064);              // 8.39MB
  u16*   aw     = (u16*)(urlB + 23068672);              // 8.39MB
  u16*   attw   = (u16*)(urlB + 31457280);              // 1.05MB
  u16*   wfT    = (u16*)(urlB + 32505856);              // 0.26MB

  (void)hipMemsetAsync(cnt2, 0, zlen, stream);

  MKArgs A;
  A.w_hh_f = w_hh_f; A.w_hh_b = w_hh_b; A.b_hh_f = b_hh_f; A.b_hh_b = b_hh_b;
  A.word_feat = word_feat; A.phrase_feat = phrase_feat; A.rel_feat = rel_feat;
  A.w_ih_f = w_ih_f; A.b_ih_f = b_ih_f; A.w_ih_b = w_ih_b; A.b_ih_b = b_ih_b;
  A.w2p_w_W = w2p_w_W; A.w2p_w_b = w2p_w_b; A.w2p_p_W = w2p_p_W; A.w2p_p_b = w2p_p_b;
  A.w2p_t_W = w2p_t_W; A.w2p_t_b = w2p_t_b;
  A.rel_W = rel_W; A.rel_b = rel_b; A.att1_W = att1_W; A.r2p_t_W = r2p_t_W;
  A.rcm = rcm; A.conn = conn;
  A.X = X; A.ctx = ctx; A.pc = pc; A.cnt2 = cnt2; A.offs = offs; A.cursor = cursor;
  A.gi_f = gi_f; A.gi_b = gi_b; A.scores = scores;
  A.wf16 = wf16; A.wih16f = wih16f; A.wih16b = wih16b; A.wl = wl; A.upd16 = upd16;
  A.W1s = W1s; A.W2s = W2s; A.W3s = W3s; A.G = G; A.V1f = V1f;
  A.A1p16 = A1p16; A.A1r16 = A1r16; A.U1 = U1; A.CB = CB; A.r2pW16 = r2pW16;
  A.pf16 = pf16; A.w2pw16 = w2pw16; A.w2pp16 = w2pp16; A.w2pt16 = w2pt16;
  A.pl = pl; A.aw = aw; A.attw = attw; A.wfT = wfT;
  A.out_phr = out_phr; A.out_urel = out_urel;

  dim3 blk(256);
  k_mega<<<256, blk, 0, stream>>>(A);

  // tail (ctx-dependent)
  k_cvec<<<256, blk, 0, stream>>>(att1_W, att1_b, ctx, cvec);
  k_edge_s<<<(2 * Rn) / 4, blk, 0, stream>>>(rcm, U1, V1f, cvec, att2_W, att2_b, sval);
  k_fill<<<(2 * Rn) / 256, blk, 0, stream>>>(rcm, sval, cursor, er, es);
  k_att_apply<<<Pn, blk, 0, stream>>>(offs, er, es, out_urel, pacc);
  k_gemm_bt<true, false, true, true, false><<<dim3(8, 32), blk, 0, stream>>>(
      pacc, Hn, r2pW16, Hn, out_phr, Hn, r2p_t_b, out_phr, Hn, nullptr, 1.f, Hn);

  (void)hipMemcpyAsync(out_word, word_feat, (size_t)Wn * Hn * 4,
                       hipMemcpyDeviceToDevice, stream);
}